// Round 2
// baseline (825.561 us; speedup 1.0000x reference)
//
#include <hip/hip_runtime.h>
#include <hip/hip_bf16.h>

#define M_ROWS 12288
#define N_COLS 12288
#define DDIM   128
#define MAXD   256          // max supported degree; Poisson(24.6) tail beyond 100 is ~0
#define INV_T  (1.0f / 0.07f)

// One WAVE per anchor row m; 4 independent waves per 256-thread block, no
// __syncthreads anywhere. Per wave:
//   1. y = xa[m] @ W          (2 output cols per lane, __shfl-broadcast xa)
//   2. ballot-compact scan of adj[m,:]  -> neighbor list in per-wave LDS
//   3. single-pass online softmax + weighted accumulate (all in registers)
__global__ __launch_bounds__(256, 4)
void layerconv_fused(const float* __restrict__ xa,
                     const float* __restrict__ inp,
                     const int*   __restrict__ adj,
                     const float* __restrict__ wgt,
                     float*       __restrict__ out)
{
    __shared__ int idx[4][MAXD];

    const int lane = threadIdx.x & 63;
    const int wid  = threadIdx.x >> 6;
    const int m    = blockIdx.x * 4 + wid;

    // ---- Phase 1: y = xa[m] @ W ; lane holds columns {2*lane, 2*lane+1} ----
    const float2 xv = ((const float2*)(xa + (size_t)m * DDIM))[lane];
    float y0 = 0.f, y1 = 0.f;
    {
        const float2* wrow = (const float2*)wgt;   // W[k][c], row = 64 float2
        #pragma unroll 8
        for (int k = 0; k < DDIM; ++k) {
            const float  xak = __shfl((k & 1) ? xv.y : xv.x, k >> 1);
            const float2 w   = wrow[(size_t)k * 64 + lane];
            y0 = fmaf(xak, w.x, y0);
            y1 = fmaf(xak, w.y, y1);
        }
    }

    // ---- Phase 2: scan adj row; ballot-compact nonzero columns into LDS ----
    int cnt = 0;
    {
        const int4* arow = (const int4*)(adj + (size_t)m * N_COLS);
        const unsigned long long lt = (1ull << lane) - 1ull;
        #pragma unroll 4
        for (int i = lane; i < N_COLS / 4; i += 64) {   // 48 exact iterations
            const int4 a = arow[i];
            const unsigned long long b0 = __ballot(a.x > 0);
            const unsigned long long b1 = __ballot(a.y > 0);
            const unsigned long long b2 = __ballot(a.z > 0);
            const unsigned long long b3 = __ballot(a.w > 0);
            if (a.x > 0) idx[wid][min(cnt + (int)__popcll(b0 & lt), MAXD - 1)] = 4*i + 0;
            cnt += (int)__popcll(b0);
            if (a.y > 0) idx[wid][min(cnt + (int)__popcll(b1 & lt), MAXD - 1)] = 4*i + 1;
            cnt += (int)__popcll(b1);
            if (a.z > 0) idx[wid][min(cnt + (int)__popcll(b2 & lt), MAXD - 1)] = 4*i + 2;
            cnt += (int)__popcll(b2);
            if (a.w > 0) idx[wid][min(cnt + (int)__popcll(b3 & lt), MAXD - 1)] = 4*i + 3;
            cnt += (int)__popcll(b3);
        }
    }
    const int cn = min(cnt, MAXD);

    // ---- Phase 3: single-pass online softmax + weighted sum (registers) ----
    float mrun = -INFINITY, lrun = 0.f, a0 = 0.f, a1 = 0.f;
    for (int j = 0; j < cn; ++j) {
        const int    n = idx[wid][j];
        const float2 v = ((const float2*)(inp + (size_t)n * DDIM))[lane];
        float s = fmaf(y0, v.x, y1 * v.y);
        #pragma unroll
        for (int off = 1; off < 64; off <<= 1) s += __shfl_xor(s, off);
        s *= INV_T;
        const float mnew  = fmaxf(mrun, s);
        const float scale = __expf(mrun - mnew);   // exp(-inf)=0 on first iter
        const float e     = __expf(s - mnew);
        lrun = fmaf(lrun, scale, e);
        a0   = fmaf(a0, scale, e * v.x);
        a1   = fmaf(a1, scale, e * v.y);
        mrun = mnew;
    }

    if (cn > 0) {
        const float inv = 1.f / lrun;
        a0 *= inv; a1 *= inv;
    } else {
        // All-masked row: softmax over identical NEG_PAD values is uniform
        // -> output is the column mean of input.
        for (int n = 0; n < N_COLS; ++n) {
            const float2 v = ((const float2*)(inp + (size_t)n * DDIM))[lane];
            a0 += v.x; a1 += v.y;
        }
        a0 *= (1.f / N_COLS); a1 *= (1.f / N_COLS);
    }
    ((float2*)(out + (size_t)m * DDIM))[lane] = make_float2(a0, a1);
}

extern "C" void kernel_launch(void* const* d_in, const int* in_sizes, int n_in,
                              void* d_out, int out_size, void* d_ws, size_t ws_size,
                              hipStream_t stream) {
    const float* xa  = (const float*)d_in[0];   // xx_anchor [M, D] fp32
    const float* inp = (const float*)d_in[1];   // input     [N, D] fp32
    const int*   adj = (const int*)d_in[2];     // adj       [M, N] int32
    const float* wgt = (const float*)d_in[3];   // weight    [D, D] fp32
    float* out = (float*)d_out;                 // out       [M, D] fp32

    layerconv_fused<<<M_ROWS / 4, 256, 0, stream>>>(xa, inp, adj, wgt, out);
}

// Round 4
// 807.026 us; speedup vs baseline: 1.0230x; 1.0230x over previous
//
#include <hip/hip_runtime.h>
#include <hip/hip_bf16.h>

#define M_ROWS 12288
#define N_COLS 12288
#define DDIM   128
#define MAXD   256          // max supported degree; Poisson(24.6) tail beyond ~100 is ~0
#define INV_T  (1.0f / 0.07f)

typedef int v4i __attribute__((ext_vector_type(4)));   // native vector: OK for nontemporal builtin

// One WAVE per anchor row m; 4 independent waves per 256-thread block, no
// __syncthreads anywhere. Neighbor-set order is irrelevant (softmax + weighted
// sum are order-invariant up to fp rounding), so compaction is UNORDERED:
// one rare LDS atomicAdd per nonzero int4 chunk (~25/wave) instead of a
// ballot-prefix chain.
__global__ __launch_bounds__(256, 4)
void layerconv_fused(const float* __restrict__ xa,
                     const float* __restrict__ inp,
                     const int*   __restrict__ adj,
                     const float* __restrict__ wgt,
                     float*       __restrict__ out)
{
    __shared__ int idx[4][MAXD];
    __shared__ int scnt[4];

    const int lane = threadIdx.x & 63;
    const int wid  = threadIdx.x >> 6;
    const int m    = blockIdx.x * 4 + wid;

    if (lane == 0) scnt[wid] = 0;   // wave-synchronous; no barrier needed

    // ---- Phase 1: y = xa[m] @ W ; lane holds columns {2*lane, 2*lane+1} ----
    const float2 xv = ((const float2*)(xa + (size_t)m * DDIM))[lane];
    float y0 = 0.f, y1 = 0.f;
    {
        const float2* wrow = (const float2*)wgt;   // W[k][c], row = 64 float2
        #pragma unroll 8
        for (int k = 0; k < DDIM; ++k) {
            const float  xak = __shfl((k & 1) ? xv.y : xv.x, k >> 1);
            const float2 w   = wrow[(size_t)k * 64 + lane];
            y0 = fmaf(xak, w.x, y0);
            y1 = fmaf(xak, w.y, y1);
        }
    }

    // ---- Phase 2: scan adj row (streamed once -> non-temporal), unordered
    //      compaction of nonzero columns into per-wave LDS list ----
    {
        const v4i* arow = (const v4i*)(adj + (size_t)m * N_COLS);
        #pragma unroll 4
        for (int i = lane; i < N_COLS / 4; i += 64) {   // 48 exact iterations
            const v4i a = __builtin_nontemporal_load(&arow[i]);
            if ((a.x | a.y | a.z | a.w) != 0) {         // ~0.8% of chunks
                const int k = (a.x > 0) + (a.y > 0) + (a.z > 0) + (a.w > 0);
                int p = atomicAdd(&scnt[wid], k);
                if (p + k <= MAXD) {
                    if (a.x > 0) idx[wid][p++] = 4*i + 0;
                    if (a.y > 0) idx[wid][p++] = 4*i + 1;
                    if (a.z > 0) idx[wid][p++] = 4*i + 2;
                    if (a.w > 0) idx[wid][p  ] = 4*i + 3;
                }
            }
        }
    }
    const int cn = min(scnt[wid], MAXD);   // same-wave LDS read; in-order

    // ---- Phase 3: single-pass online softmax + weighted sum (registers) ----
    float mrun = -INFINITY, lrun = 0.f, a0 = 0.f, a1 = 0.f;
    for (int j = 0; j < cn; ++j) {
        const int    n = idx[wid][j];
        const float2 v = ((const float2*)(inp + (size_t)n * DDIM))[lane];
        float s = fmaf(y0, v.x, y1 * v.y);
        #pragma unroll
        for (int off = 1; off < 64; off <<= 1) s += __shfl_xor(s, off);
        s *= INV_T;
        const float mnew  = fmaxf(mrun, s);
        const float scale = __expf(mrun - mnew);   // exp(-inf)=0 on first iter
        const float e     = __expf(s - mnew);
        lrun = fmaf(lrun, scale, e);
        a0   = fmaf(a0, scale, e * v.x);
        a1   = fmaf(a1, scale, e * v.y);
        mrun = mnew;
    }

    if (cn > 0) {
        const float inv = 1.f / lrun;
        a0 *= inv; a1 *= inv;
    } else {
        // All-masked row: softmax over identical NEG_PAD values is uniform
        // -> output is the column mean of input. (Probability ~0, but correct.)
        for (int n = 0; n < N_COLS; ++n) {
            const float2 v = ((const float2*)(inp + (size_t)n * DDIM))[lane];
            a0 += v.x; a1 += v.y;
        }
        a0 *= (1.f / N_COLS); a1 *= (1.f / N_COLS);
    }
    ((float2*)(out + (size_t)m * DDIM))[lane] = make_float2(a0, a1);
}

extern "C" void kernel_launch(void* const* d_in, const int* in_sizes, int n_in,
                              void* d_out, int out_size, void* d_ws, size_t ws_size,
                              hipStream_t stream) {
    const float* xa  = (const float*)d_in[0];   // xx_anchor [M, D] fp32
    const float* inp = (const float*)d_in[1];   // input     [N, D] fp32
    const int*   adj = (const int*)d_in[2];     // adj       [M, N] int32
    const float* wgt = (const float*)d_in[3];   // weight    [D, D] fp32
    float* out = (float*)d_out;                 // out       [M, D] fp32

    layerconv_fused<<<M_ROWS / 4, 256, 0, stream>>>(xa, inp, adj, wgt, out);
}